// Round 2
// baseline (145.851 us; speedup 1.0000x reference)
//
#include <hip/hip_runtime.h>

// Problem constants (fixed by the reference: LS = 8x l0 + 8x l1 + 4x l2)
#define D   52          // dim of in1/in2/out irreps
#define DD  2704        // D*D
#define HH  2000        // cb height
#define DO  52          // output dim
#define NG  8           // k-split groups for M-precompute
#define HPG (HH/NG)     // 250 h per group
#define WT_STRIDE 64    // padded row stride of transposed W

// ws layout
#define WT_BYTES   (HH * WT_STRIDE * 4)            // 512000
#define PART_BYTES (NG * DO * DD * 4)              // 4499456
#define M_BYTES    (DO * DD * 4)                   // 562432

// ---------------------------------------------------------------------------
// K0: transpose W [52][2000] -> Wt [2000][64] (padded) for scalar-load access
// ---------------------------------------------------------------------------
__global__ __launch_bounds__(256) void k_transpose_w(
    const float* __restrict__ W, float* __restrict__ Wt) {
    int idx = blockIdx.x * 256 + threadIdx.x;
    if (idx < DO * HH) {
        int o = idx / HH;
        int h = idx % HH;
        Wt[h * WT_STRIDE + o] = W[idx];
    }
}

// ---------------------------------------------------------------------------
// K1: partial M.  part[g][o][ij] = sum_{h in group g} W[o,h]*cb[h,ij]
// block: 64 ij-lanes x 4 waves (each wave = quarter of the group's h range)
// inner loop: 1 coalesced cb load + 52 FMA with SGPR (s_load) W operands
// ---------------------------------------------------------------------------
__global__ __launch_bounds__(256) void k_partial_m(
    const float* __restrict__ cb, const float* __restrict__ Wt,
    float* __restrict__ part) {
    __shared__ float red[4][64][53];  // padded to 53 -> conflict-free
    int lane = threadIdx.x & 63;
    int w    = __builtin_amdgcn_readfirstlane(threadIdx.x >> 6);  // wave id, SGPR
    int ij   = blockIdx.x * 64 + lane;
    int g    = blockIdx.y;

    int h0 = g * HPG + (HPG * w) / 4;
    int h1 = g * HPG + (HPG * (w + 1)) / 4;

    float acc[DO];
#pragma unroll
    for (int o = 0; o < DO; ++o) acc[o] = 0.f;

    bool valid = (ij < DD);
    const float* cbp = cb + ij;
    for (int h = h0; h < h1; ++h) {
        float cbv = valid ? cbp[(size_t)h * DD] : 0.f;
        const float* wrow = Wt + h * WT_STRIDE;  // h is wave-uniform -> s_load
#pragma unroll
        for (int o = 0; o < DO; ++o) acc[o] = fmaf(wrow[o], cbv, acc[o]);
    }

#pragma unroll
    for (int o = 0; o < DO; ++o) red[w][lane][o] = acc[o];
    __syncthreads();

    // 4-way reduce: thread (lane_l, oc) handles 13 o's
    int lane_l = threadIdx.x & 63;
    int oc     = threadIdx.x >> 6;
    int ij2    = blockIdx.x * 64 + lane_l;
    if (ij2 < DD) {
#pragma unroll
        for (int k = 0; k < 13; ++k) {
            int o = oc * 13 + k;
            float s = red[0][lane_l][o] + red[1][lane_l][o] +
                      red[2][lane_l][o] + red[3][lane_l][o];
            part[((size_t)g * DO + o) * DD + ij2] = s;
        }
    }
}

// ---------------------------------------------------------------------------
// K2: M[o][ij] = sum_g part[g][o][ij]
// ---------------------------------------------------------------------------
__global__ __launch_bounds__(256) void k_reduce_m(
    const float* __restrict__ part, float* __restrict__ M) {
    int idx = blockIdx.x * 256 + threadIdx.x;
    if (idx < DO * DD) {
        float s = 0.f;
#pragma unroll
        for (int g = 0; g < NG; ++g) s += part[(size_t)g * DO * DD + idx];
        M[idx] = s;
    }
}

// ---------------------------------------------------------------------------
// K3: out[b,o] = sum_{i,j} M[o, i*52+j] * in1[b,i] * in2[b,j]
// block: 64 batches (lanes) x 4 o's (waves). o wave-uniform -> M via s_load.
// in2 row in 52 VGPRs (j fully unrolled); in1 rows staged in LDS.
// ---------------------------------------------------------------------------
__global__ __launch_bounds__(256) void k_main(
    const float* __restrict__ in1, const float* __restrict__ in2,
    const float* __restrict__ M, float* __restrict__ out) {
    __shared__ float sh1[64][53];
    int lane = threadIdx.x & 63;
    int ol   = __builtin_amdgcn_readfirstlane(threadIdx.x >> 6);  // SGPR wave id
    int b0   = blockIdx.x * 64;
    int o    = blockIdx.y * 4 + ol;

    // stage in1 rows for the block's 64 batches
    for (int t = threadIdx.x; t < 64 * D; t += 256) {
        int bl = t / D, i = t % D;
        sh1[bl][i] = in1[(size_t)(b0 + bl) * D + i];
    }

    // in2 row of this thread's batch into registers (13 aligned float4 loads)
    int b = b0 + lane;
    float r2[D];
    const float4* p2 = reinterpret_cast<const float4*>(in2 + (size_t)b * D);
#pragma unroll
    for (int q = 0; q < 13; ++q) {
        float4 v = p2[q];
        r2[4 * q + 0] = v.x; r2[4 * q + 1] = v.y;
        r2[4 * q + 2] = v.z; r2[4 * q + 3] = v.w;
    }
    __syncthreads();

    const float* Mrow = M + (size_t)o * DD;  // o wave-uniform -> scalar loads
    float acc = 0.f;
    for (int i = 0; i < D; ++i) {
        float a1 = sh1[lane][i];
        const float* mp = Mrow + i * D;
        float p0 = 0.f, p1 = 0.f, p2s = 0.f, p3 = 0.f;
#pragma unroll
        for (int j = 0; j < D; j += 4) {
            p0  = fmaf(mp[j + 0], r2[j + 0], p0);
            p1  = fmaf(mp[j + 1], r2[j + 1], p1);
            p2s = fmaf(mp[j + 2], r2[j + 2], p2s);
            p3  = fmaf(mp[j + 3], r2[j + 3], p3);
        }
        acc = fmaf(a1, (p0 + p1) + (p2s + p3), acc);
    }
    out[(size_t)b * DO + o] = acc;
}

// ---------------------------------------------------------------------------
extern "C" void kernel_launch(void* const* d_in, const int* in_sizes, int n_in,
                              void* d_out, int out_size, void* d_ws, size_t ws_size,
                              hipStream_t stream) {
    const float* in1 = (const float*)d_in[0];
    const float* in2 = (const float*)d_in[1];
    const float* cb  = (const float*)d_in[2];
    const float* W   = (const float*)d_in[3];
    float* out = (float*)d_out;

    int B = in_sizes[0] / D;  // 4096

    char* ws   = (char*)d_ws;
    float* Wt   = (float*)(ws);
    float* part = (float*)(ws + WT_BYTES);
    float* M    = (float*)(ws + WT_BYTES + PART_BYTES);
    // needs WT_BYTES + PART_BYTES + M_BYTES ~= 5.6 MB of ws

    hipLaunchKernelGGL(k_transpose_w, dim3((DO * HH + 255) / 256), dim3(256), 0,
                       stream, W, Wt);
    hipLaunchKernelGGL(k_partial_m, dim3((DD + 63) / 64, NG), dim3(256), 0,
                       stream, cb, Wt, part);
    hipLaunchKernelGGL(k_reduce_m, dim3((DO * DD + 255) / 256), dim3(256), 0,
                       stream, part, M);
    hipLaunchKernelGGL(k_main, dim3(B / 64, 13), dim3(256), 0,
                       stream, in1, in2, M, out);
}